// Round 7
// baseline (404.457 us; speedup 1.0000x reference)
//
#include <hip/hip_runtime.h>
#include <math.h>

// x (2,16,2048,2048) fp32 -> d_out flat fp32 concat:
//   out  = softmax(x, -1)                [134217728]
//   q    = 64x64 blockwise int8 (as f32) [134217728]
//   s    = per-block scale               [32768]
//   z    = per-block zero                [32768]
//
// Write-allocate L3 strategy: K1 does the FULL softmax (wave-per-row, row in
// registers) and writes `out` with normal stores (MALL-allocates), plus
// per-64x64-tile min/max -> s/z/szbuf. K2 is a pure streaming quantizer that
// re-reads `out` -- freshly DIRTY in Infinity Cache from K1 of the same
// 134 MB chunk -- and NT-stores q. Read-then-read reuse measured ~0 (R4/R6);
// this tests write-then-read reuse. Worst case traffic-neutral vs R4.

static constexpr int  COLS      = 2048;
static constexpr long long OUT_ELEMS = 134217728LL;
static constexpr int  NBLK      = 32768;    // 32*32*32 quant tiles
static constexpr int  NCHUNK    = 4;
static constexpr int  STRIPS_PER_CHUNK = 256;   // 1024 strips / 4
static constexpr int  PANELS_PER_CHUNK = 2048;  // 8192 panels / 4

using v4f = __attribute__((ext_vector_type(4))) float;

// ---------------- Kernel 1: full softmax + per-tile stats --------------------
// Block = one 64-row strip (16 waves; wave w does rows rr*16+w, rr=0..3).
// Each wave holds its entire row (8 x float4), computes max & 1/sum, writes
// p = exp(x-m)/sum straight to out (cached stores), and per-tile min/max of
// p into LDS. Phase B: wave w reduces tiles 2w, 2w+1 over 64 rows -> s,z.
__global__ __launch_bounds__(1024) void softmax_stats_kernel(
    const float* __restrict__ x, float* __restrict__ out,
    float* __restrict__ sout, float* __restrict__ zout,
    float2* __restrict__ szbuf, int chunk)
{
    const int strip = chunk * STRIPS_PER_CHUNK + blockIdx.x;  // 0..1023
    const int n = strip >> 5;          // batch*head
    const int i = strip & 31;          // row-block
    const int t = threadIdx.x;
    const int w = t >> 6;              // wave 0..15
    const int l = t & 63;

    const long long xbase = (long long)n * (COLS * (long long)COLS)
                          + (long long)(i * 64) * COLS;

    __shared__ float2 sT[64][32];      // per-(row, tile) {mn, mx} of p; 16 KB

#pragma unroll
    for (int rr = 0; rr < 4; ++rr) {
        const int r = rr * 16 + w;
        const float* rp = x + xbase + (long long)r * COLS;

        float4 v[8];
#pragma unroll
        for (int c = 0; c < 8; ++c)
            v[c] = *reinterpret_cast<const float4*>(rp + c * 256 + l * 4);

        float m = -INFINITY;
#pragma unroll
        for (int c = 0; c < 8; ++c)
            m = fmaxf(m, fmaxf(fmaxf(v[c].x, v[c].y), fmaxf(v[c].z, v[c].w)));
#pragma unroll
        for (int off = 32; off >= 1; off >>= 1)
            m = fmaxf(m, __shfl_xor(m, off, 64));

        float s = 0.0f;
#pragma unroll
        for (int c = 0; c < 8; ++c)
            s += __expf(v[c].x - m) + __expf(v[c].y - m) +
                 __expf(v[c].z - m) + __expf(v[c].w - m);
#pragma unroll
        for (int off = 32; off >= 1; off >>= 1)
            s += __shfl_xor(s, off, 64);
        const float rcp = 1.0f / s;

        float* op = out + xbase + (long long)r * COLS;
#pragma unroll
        for (int c = 0; c < 8; ++c) {
            float4 pv;
            pv.x = __expf(v[c].x - m) * rcp;
            pv.y = __expf(v[c].y - m) * rcp;
            pv.z = __expf(v[c].z - m) * rcp;
            pv.w = __expf(v[c].w - m) * rcp;
            // NORMAL store: allocate in Infinity Cache for K2's read-back.
            *reinterpret_cast<float4*>(op + c * 256 + l * 4) = pv;

            float tmn = fminf(fminf(pv.x, pv.y), fminf(pv.z, pv.w));
            float tmx = fmaxf(fmaxf(pv.x, pv.y), fmaxf(pv.z, pv.w));
            // reduce within 16-lane group = one 64-col tile
#pragma unroll
            for (int off = 8; off >= 1; off >>= 1) {
                tmn = fminf(tmn, __shfl_xor(tmn, off, 64));
                tmx = fmaxf(tmx, __shfl_xor(tmx, off, 64));
            }
            if ((l & 15) == 0)
                sT[r][4 * c + (l >> 4)] = make_float2(tmn, tmx);
        }
    }
    __syncthreads();

    // Phase B: per-tile reduce over 64 rows; wave w -> tiles 2w, 2w+1.
#pragma unroll
    for (int jj = 0; jj < 2; ++jj) {
        const int j = 2 * w + jj;
        const float2 vv = sT[l][j];
        float mn = vv.x, mx = vv.y;
#pragma unroll
        for (int off = 32; off >= 1; off >>= 1) {
            mn = fminf(mn, __shfl_xor(mn, off, 64));
            mx = fmaxf(mx, __shfl_xor(mx, off, 64));
        }
        if (l == 0) {
            const float sc = (mx - mn) / 255.0f;
            const float d  = sc + 1e-10f;
            const float zz = -mn / d - 128.0f;
            const int g = (n << 10) + (i << 5) + j;
            sout[g] = sc;
            zout[g] = zz;
            szbuf[g] = make_float2(zz, 1.0f / d);
        }
    }
}

// ---------------- Kernel 2: streaming quantizer ------------------------------
// 64x256 panel per 256-thread block; no LDS, no barriers, no exp. Reads out
// (L3-dirty from K1 of this chunk), NT-stores q.
__global__ __launch_bounds__(256) void quant_kernel(
    const float* __restrict__ out, const float2* __restrict__ szbuf,
    float* __restrict__ qout, int chunk)
{
    const int p  = chunk * PANELS_PER_CHUNK + blockIdx.x;  // global panel id
    const int n  = p >> 8;
    const int i  = (p >> 3) & 31;
    const int jg = p & 7;
    const int t  = threadIdx.x;
    const int w  = t >> 6;
    const int l  = t & 63;

    const long long obase = (long long)n * (COLS * (long long)COLS)
                          + (long long)(i * 64) * COLS + jg * 256;
    const int tile4 = (n << 10) + (i << 5) + (jg << 2);
    const float2 sz = szbuf[tile4 + (l >> 4)];   // {z, 1/(s+eps)}

    float* __restrict__ qb = qout + (long long)tile4 * 4096
                           + (l >> 4) * 4096 + (l & 15) * 4;

#pragma unroll
    for (int k = 0; k < 16; ++k) {
        const int r = 4 * k + w;
        const float4 pv = *reinterpret_cast<const float4*>(
            out + obase + (long long)r * COLS + l * 4);
        float4 qv;
        qv.x = roundf(fminf(fmaxf(pv.x * sz.y + sz.x, -128.0f), 127.0f));
        qv.y = roundf(fminf(fmaxf(pv.y * sz.y + sz.x, -128.0f), 127.0f));
        qv.z = roundf(fminf(fmaxf(pv.z * sz.y + sz.x, -128.0f), 127.0f));
        qv.w = roundf(fminf(fmaxf(pv.w * sz.y + sz.x, -128.0f), 127.0f));
        __builtin_nontemporal_store(*(const v4f*)&qv, (v4f*)(qb + r * 64));
    }
}

extern "C" void kernel_launch(void* const* d_in, const int* in_sizes, int n_in,
                              void* d_out, int out_size, void* d_ws, size_t ws_size,
                              hipStream_t stream) {
    const float* x = (const float*)d_in[0];
    float* out  = (float*)d_out;
    float* qout = out + OUT_ELEMS;
    float* sout = qout + OUT_ELEMS;
    float* zout = sout + NBLK;
    float2* szbuf = (float2*)d_ws;   // 32768 * 8 B = 256 KB

    for (int c = 0; c < NCHUNK; ++c) {
        softmax_stats_kernel<<<STRIPS_PER_CHUNK, 1024, 0, stream>>>(
            x, out, sout, zout, szbuf, c);
        quant_kernel<<<PANELS_PER_CHUNK, 256, 0, stream>>>(
            out, szbuf, qout, c);
    }
}

// Round 8
// 349.500 us; speedup vs baseline: 1.1572x; 1.1572x over previous
//
#include <hip/hip_runtime.h>
#include <math.h>

// x (2,16,2048,2048) fp32 -> d_out flat fp32 concat:
//   out  = softmax(x, -1)                [134217728]
//   q    = 64x64 blockwise int8 (as f32) [134217728]
//   s    = per-block scale               [32768]
//   z    = per-block zero                [32768]
//
// Best measured structure (R4, 356.5 us = ~95% of the 2.15 GB traffic floor):
// two lean kernels. K1: wave-per-row stats (cached loads populate L3 tail).
// K2: 64x256 panels, REVERSE block order to harvest the L3-resident tail of
// x, NT loads for the rest, NT stores throughout. Cross-kernel L3 reuse
// beyond this was tested (chunked interleave R6, write-readback R7) and
// regressed; fusion (R5) regressed on 1-block/CU barrier drain.

static constexpr int  COLS      = 2048;
static constexpr long long OUT_ELEMS = 134217728LL;
static constexpr int  NROWS     = 65536;   // 32 * 2048
static constexpr int  NBLK      = 32768;   // 32 * 32 * 32

using v4f = __attribute__((ext_vector_type(4))) float;

// ---------------- Kernel 1: per-row max and 1/sum(exp(x-max)) ----------------
__global__ __launch_bounds__(256) void rowstats_kernel(
    const float* __restrict__ x, float* __restrict__ stats)
{
    const int lane = threadIdx.x & 63;
    const int wave = threadIdx.x >> 6;
    const long long row = (long long)blockIdx.x * 4 + wave;
    const float* rp = x + row * COLS;

    float4 v[8];
#pragma unroll
    for (int c = 0; c < 8; ++c)
        v[c] = *reinterpret_cast<const float4*>(rp + c * 256 + lane * 4);

    float m = -INFINITY;
#pragma unroll
    for (int c = 0; c < 8; ++c)
        m = fmaxf(m, fmaxf(fmaxf(v[c].x, v[c].y), fmaxf(v[c].z, v[c].w)));
#pragma unroll
    for (int off = 32; off >= 1; off >>= 1)
        m = fmaxf(m, __shfl_xor(m, off, 64));

    float s = 0.0f;
#pragma unroll
    for (int c = 0; c < 8; ++c)
        s += __expf(v[c].x - m) + __expf(v[c].y - m) +
             __expf(v[c].z - m) + __expf(v[c].w - m);
#pragma unroll
    for (int off = 32; off >= 1; off >>= 1)
        s += __shfl_xor(s, off, 64);

    if (lane == 0) {
        stats[row * 2 + 0] = m;
        stats[row * 2 + 1] = 1.0f / s;
    }
}

// ---------------- Kernel 2: 64x256 panel = 4 column-tiles per block ----------
__global__ __launch_bounds__(256) void panel_kernel(
    const float* __restrict__ x, const float* __restrict__ stats,
    float* __restrict__ out, float* __restrict__ qout,
    float* __restrict__ sout, float* __restrict__ zout)
{
    const int b  = 8191 - blockIdx.x;  // reverse traversal: harvest L3 tail
    const int n  = b >> 8;             // 0..31
    const int i  = (b >> 3) & 31;      // row-block
    const int jg = b & 7;              // group of 4 column-tiles
    const int t  = threadIdx.x;
    const int w  = t >> 6;             // wave 0..3
    const int l  = t & 63;

    const long long xbase = (long long)n * (COLS * (long long)COLS)
                          + (long long)(i * 64) * COLS + jg * 256;
    const int growbase = (n << 11) + i * 64;

    float4 p[16];
    float mn = INFINITY, mx = -INFINITY;
#pragma unroll
    for (int k = 0; k < 16; ++k) {
        const int r = (k << 2) + w;
        const float2 st = *reinterpret_cast<const float2*>(
            stats + (long long)(growbase + r) * 2);
        const v4f v = __builtin_nontemporal_load(
            (const v4f*)(x + xbase + (long long)r * COLS + l * 4));
        float4 pv;
        pv.x = __expf(v.x - st.x) * st.y;
        pv.y = __expf(v.y - st.x) * st.y;
        pv.z = __expf(v.z - st.x) * st.y;
        pv.w = __expf(v.w - st.x) * st.y;
        p[k] = pv;
        mn = fminf(mn, fminf(fminf(pv.x, pv.y), fminf(pv.z, pv.w)));
        mx = fmaxf(mx, fmaxf(fmaxf(pv.x, pv.y), fmaxf(pv.z, pv.w)));
    }
    // reduce within each 16-lane group (one group per tile)
#pragma unroll
    for (int off = 8; off >= 1; off >>= 1) {
        mn = fminf(mn, __shfl_xor(mn, off, 64));
        mx = fmaxf(mx, __shfl_xor(mx, off, 64));
    }

    __shared__ float  smn[4][4], smx[4][4];   // [wave][tile]
    __shared__ float2 sbc[4];                 // per tile: {z, 1/(s+eps)}
    if ((l & 15) == 0) { smn[w][l >> 4] = mn; smx[w][l >> 4] = mx; }
    __syncthreads();
    if (t < 4) {
        const float bmn = fminf(fminf(smn[0][t], smn[1][t]),
                                fminf(smn[2][t], smn[3][t]));
        const float bmx = fmaxf(fmaxf(smx[0][t], smx[1][t]),
                                fmaxf(smx[2][t], smx[3][t]));
        const float sc = (bmx - bmn) / 255.0f;
        const float d  = sc + 1e-10f;
        const float zz = -bmn / d - 128.0f;
        const int b4 = (n << 10) + (i << 5) + (jg << 2) + t;
        sout[b4] = sc;
        zout[b4] = zz;
        sbc[t] = make_float2(zz, 1.0f / d);
    }
    __syncthreads();

    const int   tl  = l >> 4;
    const float2 bc = sbc[tl];
    float* __restrict__ qb = qout
        + (long long)((n << 10) + (i << 5) + (jg << 2)) * 4096
        + tl * 4096 + (l & 15) * 4;

#pragma unroll
    for (int k = 0; k < 16; ++k) {
        const int r = (k << 2) + w;
        const float4 pv = p[k];
        __builtin_nontemporal_store(*(const v4f*)&pv,
            (v4f*)(out + xbase + (long long)r * COLS + l * 4));
        float4 qv;
        qv.x = roundf(fminf(fmaxf(pv.x * bc.y + bc.x, -128.0f), 127.0f));
        qv.y = roundf(fminf(fmaxf(pv.y * bc.y + bc.x, -128.0f), 127.0f));
        qv.z = roundf(fminf(fmaxf(pv.z * bc.y + bc.x, -128.0f), 127.0f));
        qv.w = roundf(fminf(fmaxf(pv.w * bc.y + bc.x, -128.0f), 127.0f));
        __builtin_nontemporal_store(*(const v4f*)&qv, (v4f*)(qb + r * 64));
    }
}

extern "C" void kernel_launch(void* const* d_in, const int* in_sizes, int n_in,
                              void* d_out, int out_size, void* d_ws, size_t ws_size,
                              hipStream_t stream) {
    const float* x = (const float*)d_in[0];
    float* out  = (float*)d_out;
    float* qout = out + OUT_ELEMS;
    float* sout = qout + OUT_ELEMS;
    float* zout = sout + NBLK;
    float* stats = (float*)d_ws;   // NROWS * 2 floats = 512 KB

    rowstats_kernel<<<NROWS / 4, 256, 0, stream>>>(x, stats);
    panel_kernel<<<8192, 256, 0, stream>>>(x, stats, out, qout, sout, zout);
}